// Round 6
// baseline (389.452 us; speedup 1.0000x reference)
//
#include <hip/hip_runtime.h>

typedef unsigned short u16;
typedef unsigned int   u32;
typedef __bf16 bf16x8 __attribute__((ext_vector_type(8)));
typedef u16    u16x8  __attribute__((ext_vector_type(8)));
typedef float  f32x4  __attribute__((ext_vector_type(4)));

#define T_TOT  65536
#define NSEG   64
#define NH     16
#define DD     128
#define LL     64
#define BT     64
#define CHUNK  512           // frames per block
#define NTILE  8             // CHUNK / BT
#define NCHUNK 128           // T_TOT / CHUNK
#define LDA    136           // u16 row stride (272 B)
#define SCALE  11.313708498984761f   // sqrt(128)

__device__ __forceinline__ u16 f2bf_rne(float x){
    u32 u = __float_as_uint(x);
    u32 r = u + 0x7fffu + ((u >> 16) & 1u);
    return (u16)(r >> 16);
}
__device__ __forceinline__ float bf2f(u16 h){
    return __uint_as_float(((u32)h) << 16);
}
__device__ __forceinline__ float fast_tanh(float x){
    float e = __builtin_amdgcn_exp2f(x * 2.8853900817779268f);  // 2*log2(e)
    return 1.0f - 2.0f * __builtin_amdgcn_rcpf(1.0f + e);
}

// sum across the 16-lane row group via DPP (no LDS-unit traffic)
__device__ __forceinline__ float row16_sum(float x){
    int v;
    v = __builtin_amdgcn_update_dpp(0, __float_as_int(x), 0xB1, 0xf, 0xf, true);  // quad_perm(1,0,3,2)
    x += __int_as_float(v);
    v = __builtin_amdgcn_update_dpp(0, __float_as_int(x), 0x4E, 0xf, 0xf, true);  // quad_perm(2,3,0,1)
    x += __int_as_float(v);
    v = __builtin_amdgcn_update_dpp(0, __float_as_int(x), 0x124, 0xf, 0xf, true); // row_ror:4
    x += __int_as_float(v);
    v = __builtin_amdgcn_update_dpp(0, __float_as_int(x), 0x128, 0xf, 0xf, true); // row_ror:8
    x += __int_as_float(v);
    return x;
}

// split 8 fp32 -> bf16 hi + lo (error-compensated), in registers
__device__ __forceinline__ void cvt8(const float4 a, const float4 b,
                                     bf16x8& hi, bf16x8& lo){
    float xs[8] = {a.x, a.y, a.z, a.w, b.x, b.y, b.z, b.w};
    union { u16x8 u; bf16x8 b; } H, L;
    #pragma unroll
    for (int j = 0; j < 8; ++j){
        u32 u = __float_as_uint(xs[j]);
        u32 r = u + 0x7fffu + ((u >> 16) & 1u);
        H.u[j] = (u16)(r >> 16);
        float d = xs[j] - __uint_as_float(r & 0xffff0000u);
        u32 v = __float_as_uint(d);
        u32 s = v + 0x7fffu + ((v >> 16) & 1u);
        L.u[j] = (u16)(s >> 16);
    }
    hi = H.b; lo = L.b;
}

// ---------------- prep: split V into bf16 hi/lo + zero accumulators ----------------
__global__ void prep_split(const float* __restrict__ V,
                           u16* __restrict__ Vh, u16* __restrict__ Vl,
                           float* __restrict__ hsum, float* __restrict__ denom){
    int idx = blockIdx.x * 256 + threadIdx.x;   // 131072 threads
    float x = V[idx];
    u16 hi = f2bf_rne(x);
    Vh[idx] = hi;
    Vl[idx] = f2bf_rne(x - bf2f(hi));
    hsum[idx] = 0.0f;                            // hsum is exactly 131072 floats
    if (idx < NSEG * NH) denom[idx] = 0.0f;
}

// accumulate one strip's contribution: racc[r] += em * hq[col][d(r)]  (per-lane, no cross-lane)
#define ACCUM(EM) do {                                                       \
    dnp += (EM);                                                             \
    _Pragma("unroll")                                                        \
    for (int ks_ = 0; ks_ < 4; ++ks_){                                       \
        _Pragma("unroll")                                                    \
        for (int j_ = 0; j_ < 8; ++j_)                                       \
            racc[ks_ * 8 + j_] += (EM) * (float)aHk[ks_][j_];                \
    }                                                                        \
} while(0)

// flush accumulated segment: DPP-reduce across the 16-lane col group, then masked atomics
#define FLUSH() do { if (cur >= 0){                                          \
    _Pragma("unroll")                                                        \
    for (int r_ = 0; r_ < 32; ++r_) racc[r_] = row16_sum(racc[r_]);          \
    float dsum_ = row16_sum(dnp);                                            \
    float* base_ = hsum + ((size_t)cur * NH + h) * DD + kb * 8;              \
    _Pragma("unroll")                                                        \
    for (int r_ = 0; r_ < 32; ++r_)                                          \
        if (col == (r_ & 15)) atomicAdd(base_ + (r_ >> 3) * 32 + (r_ & 7), racc[r_]); \
    if (lane == 0) atomicAdd(&denom[cur * NH + h], dsum_);                   \
    _Pragma("unroll")                                                        \
    for (int r_ = 0; r_ < 32; ++r_) racc[r_] = 0.f;                          \
    dnp = 0.f;                                                               \
} } while(0)

// ---------------- main: persistent per-head blocks, in-register segment reduction ----------------
__global__ __launch_bounds__(256, 2) void medvid_main(
    const float* __restrict__ videos, const int* __restrict__ segids,
    const u16* __restrict__ Vh, const u16* __restrict__ Vl,
    const float* __restrict__ w,
    float* __restrict__ hsum, float* __restrict__ denom)
{
    __shared__ u16 sBl[LL * LDA];   // B-lo tile (17.4 KB)

    const int tid  = threadIdx.x;
    const int h    = blockIdx.y;
    const int c0   = blockIdx.x * CHUNK;
    const int lane = tid & 63;
    const int wv   = tid >> 6;      // wave id = 16-frame strip within tile
    const int col  = lane & 15;
    const int kb   = lane >> 4;

    // ---- stage B-lo into LDS ----
    #pragma unroll
    for (int i = 0; i < 4; ++i){
        int idx = i * 256 + tid;            // 1024 chunks of 16 B
        int l = idx >> 4, c = idx & 15;
        *(uint4*)(sBl + l * LDA + c * 8) = *(const uint4*)(Vl + (h * LL + l) * DD + c * 8);
    }

    // ---- B-hi fragments in registers (64 VGPR) ----
    bf16x8 bh[4][4];
    #pragma unroll
    for (int ks = 0; ks < 4; ++ks){
        #pragma unroll
        for (int nt = 0; nt < 4; ++nt)
            bh[ks][nt] = *(const bf16x8*)(Vh + (h * LL + nt * 16 + col) * DD + kb * 8 + ks * 32);
    }
    float wl[4];
    #pragma unroll
    for (int nt = 0; nt < 4; ++nt) wl[nt] = w[h * LL + nt * 16 + col];

    // ---- this wave's 128 segment ids (2 regs/lane): lane (kb,col) -> frame c0+kb*64+wv*16+col (+256) ----
    const int segbase = c0 + kb * 64 + wv * 16 + col;
    const int mseg0 = segids[segbase];
    const int mseg1 = segids[segbase + 256];

    // ---- prologue: tile 0 A loads (depth-1 pipeline, known-good) ----
    const float* arow = videos + (size_t)(c0 + wv * 16 + col) * 2048 + h * DD + kb * 8;
    float4 av[8];
    #pragma unroll
    for (int q = 0; q < 4; ++q){
        av[2*q]   = *(const float4*)(arow + q * 32);
        av[2*q+1] = *(const float4*)(arow + q * 32 + 4);
    }

    __syncthreads();   // sBl visible

    float racc[32];
    #pragma unroll
    for (int r = 0; r < 32; ++r) racc[r] = 0.f;
    float dnp = 0.f;
    int   cur = -1;

    for (int t = 0; t < NTILE; ++t){
        // ---- MFMA: pre-tanh alpha [16 x 64], bf16x3 compensated; keep aH for the weighted sum ----
        f32x4 acc[4] = {};
        bf16x8 aHk[4];
        #pragma unroll
        for (int ks = 0; ks < 4; ++ks){
            bf16x8 aL;
            cvt8(av[2*ks], av[2*ks+1], aHk[ks], aL);
            #pragma unroll
            for (int nt = 0; nt < 4; ++nt){
                bf16x8 bL = *(const bf16x8*)(sBl + (nt * 16 + col) * LDA + kb * 8 + ks * 32);
                acc[nt] = __builtin_amdgcn_mfma_f32_16x16x32_bf16(aHk[ks], bh[ks][nt], acc[nt], 0, 0, 0);
                acc[nt] = __builtin_amdgcn_mfma_f32_16x16x32_bf16(aL,      bh[ks][nt], acc[nt], 0, 0, 0);
                acc[nt] = __builtin_amdgcn_mfma_f32_16x16x32_bf16(aHk[ks], bL,         acc[nt], 0, 0, 0);
            }
        }
        // ---- prefetch next tile's A ----
        if (t + 1 < NTILE){
            const float* nrow = arow + (size_t)(t + 1) * BT * 2048;
            #pragma unroll
            for (int q = 0; q < 4; ++q){
                av[2*q]   = *(const float4*)(nrow + q * 32);
                av[2*q+1] = *(const float4*)(nrow + q * 32 + 4);
            }
        }
        // ---- tanh -> *w -> DPP reduce over L -> e (frame kb*4+r, replicated in group) ----
        float e4[4];
        #pragma unroll
        for (int r = 0; r < 4; ++r){
            float s = 0.f;
            #pragma unroll
            for (int nt = 0; nt < 4; ++nt)
                s += fast_tanh(acc[nt][r]) * wl[nt];
            s = row16_sum(s);
            e4[r] = __builtin_amdgcn_exp2f(s * 1.4426950408889634f);
        }
        // ---- transpose e: lane needs e of frame 'col' (lives in group col>>2, slot col&3) ----
        const int srcl = ((col >> 2) * 16) + col;
        float b0 = __shfl(e4[0], srcl);
        float b1 = __shfl(e4[1], srcl);
        float b2 = __shfl(e4[2], srcl);
        float b3 = __shfl(e4[3], srcl);
        float ec = (col & 2) ? ((col & 1) ? b3 : b2) : ((col & 1) ? b1 : b0);

        // ---- segment ids for this strip; fast path: whole strip one segment ----
        const int msel = (t < 4) ? mseg0 : mseg1;
        const int segc = __shfl(msel, (t & 3) * 16 + col);   // seg of frame 'col'
        const int s0   = __builtin_amdgcn_readfirstlane(segc);
        unsigned long long nb = __ballot(segc != s0);
        if (nb == 0ULL){
            if (s0 != cur){ FLUSH(); cur = s0; }
            ACCUM(ec);
        } else {
            int sc = s0;
            for (;;){
                if (sc != cur){ FLUSH(); cur = sc; }
                float em = (segc == sc) ? ec : 0.f;
                ACCUM(em);
                unsigned long long bm = __ballot(segc > sc);
                if (bm == 0ULL) break;
                sc = __builtin_amdgcn_readlane(segc, (int)__ffsll(bm) - 1);
            }
        }
    }
    FLUSH();
}

// ---------------- finalize ----------------
__global__ void finalize(const float* __restrict__ hsum, const float* __restrict__ denom,
                         const float* __restrict__ W_out, const float* __restrict__ b_out,
                         float* __restrict__ out)
{
    const int s = blockIdx.x;
    const int tid = threadIdx.x;
    float part = 0.f;
    for (int f = tid; f < 2048; f += 256){
        int hh = f >> 7, d = f & 127;
        float den = denom[s * NH + hh];
        if (den > 0.f)
            part += hsum[((size_t)s * NH + hh) * DD + d] / (den * SCALE) * W_out[f];
    }
    #pragma unroll
    for (int m = 1; m < 64; m <<= 1) part += __shfl_xor(part, m, 64);
    __shared__ float red[4];
    if ((tid & 63) == 0) red[tid >> 6] = part;
    __syncthreads();
    if (tid == 0) out[s] = red[0] + red[1] + red[2] + red[3] + b_out[0];
}

extern "C" void kernel_launch(void* const* d_in, const int* in_sizes, int n_in,
                              void* d_out, int out_size, void* d_ws, size_t ws_size,
                              hipStream_t stream)
{
    const float* videos = (const float*)d_in[0];
    const int*   segids = (const int*)  d_in[1];
    const float* V      = (const float*)d_in[2];
    const float* w      = (const float*)d_in[3];
    const float* W_out  = (const float*)d_in[4];
    const float* b_out  = (const float*)d_in[5];
    float* out = (float*)d_out;

    // ws layout: hsum[S*H*D] f32 | denom[S*H] f32 | Vh[H*L*D] u16 | Vl[H*L*D] u16
    float* hsum  = (float*)d_ws;
    float* denom = hsum + (NSEG * NH * DD);
    u16*   Vh    = (u16*)(denom + NSEG * NH);
    u16*   Vl    = Vh + (NH * LL * DD);

    prep_split<<<dim3((NH * LL * DD) / 256), dim3(256), 0, stream>>>(V, Vh, Vl, hsum, denom);
    medvid_main<<<dim3(NCHUNK, NH), dim3(256), 0, stream>>>(videos, segids, Vh, Vl, w, hsum, denom);
    finalize<<<dim3(NSEG), dim3(256), 0, stream>>>(hsum, denom, W_out, b_out, out);
}

// Round 7
// 261.715 us; speedup vs baseline: 1.4881x; 1.4881x over previous
//
#include <hip/hip_runtime.h>

typedef unsigned short u16;
typedef unsigned int   u32;
typedef __bf16 bf16x8 __attribute__((ext_vector_type(8)));
typedef u16    u16x8  __attribute__((ext_vector_type(8)));
typedef float  f32x4  __attribute__((ext_vector_type(4)));

#define T_TOT  65536
#define NSEG   64
#define NH     16
#define DD     128
#define LL     64
#define BT     64
#define CHUNK  512           // frames per block
#define NTILE  8             // CHUNK / BT
#define NCHUNK 128           // T_TOT / CHUNK
#define LDA    136           // u16 row stride (272 B): (col+kb)%8 uniform over bank-quads -> b128 conflict-free
#define SCALE  11.313708498984761f   // sqrt(128)

__device__ __forceinline__ u16 f2bf_rne(float x){
    u32 u = __float_as_uint(x);
    u32 r = u + 0x7fffu + ((u >> 16) & 1u);
    return (u16)(r >> 16);
}
__device__ __forceinline__ float bf2f(u16 h){
    return __uint_as_float(((u32)h) << 16);
}
__device__ __forceinline__ float fast_tanh(float x){
    float e = __builtin_amdgcn_exp2f(x * 2.8853900817779268f);  // 2*log2(e)
    return 1.0f - 2.0f * __builtin_amdgcn_rcpf(1.0f + e);
}

// split 8 fp32 -> bf16 hi + lo (error-compensated), in registers
__device__ __forceinline__ void cvt8(const float4 a, const float4 b,
                                     bf16x8& hi, bf16x8& lo){
    float xs[8] = {a.x, a.y, a.z, a.w, b.x, b.y, b.z, b.w};
    union { u16x8 u; bf16x8 b; } H, L;
    #pragma unroll
    for (int j = 0; j < 8; ++j){
        u32 u = __float_as_uint(xs[j]);
        u32 r = u + 0x7fffu + ((u >> 16) & 1u);
        H.u[j] = (u16)(r >> 16);
        float d = xs[j] - __uint_as_float(r & 0xffff0000u);
        u32 v = __float_as_uint(d);
        u32 s = v + 0x7fffu + ((v >> 16) & 1u);
        L.u[j] = (u16)(s >> 16);
    }
    hi = H.b; lo = L.b;
}

// ---------------- prep: split V into bf16 hi/lo + zero accumulators ----------------
__global__ void prep_split(const float* __restrict__ V,
                           u16* __restrict__ Vh, u16* __restrict__ Vl,
                           float* __restrict__ hsum, float* __restrict__ denom){
    int idx = blockIdx.x * 256 + threadIdx.x;   // 131072 threads
    float x = V[idx];
    u16 hi = f2bf_rne(x);
    Vh[idx] = hi;
    Vl[idx] = f2bf_rne(x - bf2f(hi));
    hsum[idx] = 0.0f;                            // hsum is exactly 131072 floats
    if (idx < NSEG * NH) denom[idx] = 0.0f;
}

// ---------------- main: R3 structure; B-lo in LDS, cvt up-front, 3 waves/SIMD ----------------
__global__ __launch_bounds__(256, 3) void medvid_main(
    const float* __restrict__ videos, const int* __restrict__ segids,
    const u16* __restrict__ Vh, const u16* __restrict__ Vl,
    const float* __restrict__ w,
    float* __restrict__ hsum, float* __restrict__ denom)
{
    __shared__ u16 sAh[BT * LDA];   // A-hi park, per-wave 16-row regions (17.4 KB)
    __shared__ u16 sBl[LL * LDA];   // B-lo tile (17.4 KB)

    const int tid  = threadIdx.x;
    const int h    = blockIdx.y;
    const int c0   = blockIdx.x * CHUNK;
    const int lane = tid & 63;
    const int wv   = tid >> 6;      // wave id = 16-frame strip within tile
    const int col  = lane & 15;
    const int kb   = lane >> 4;

    // ---- stage B-lo into LDS (shared by all 4 waves) ----
    #pragma unroll
    for (int i = 0; i < 4; ++i){
        int idx = i * 256 + tid;            // 1024 chunks of 16 B
        int l = idx >> 4, c = idx & 15;
        *(uint4*)(sBl + l * LDA + c * 8) = *(const uint4*)(Vl + (h * LL + l) * DD + c * 8);
    }

    // ---- B-hi fragments in registers (64 VGPR) ----
    bf16x8 bh[4][4];
    #pragma unroll
    for (int ks = 0; ks < 4; ++ks){
        #pragma unroll
        for (int nt = 0; nt < 4; ++nt)
            bh[ks][nt] = *(const bf16x8*)(Vh + (h * LL + nt * 16 + col) * DD + kb * 8 + ks * 32);
    }
    float wl[4];
    #pragma unroll
    for (int nt = 0; nt < 4; ++nt) wl[nt] = w[h * LL + nt * 16 + col];

    // ---- this wave's 128 segment ids (2 regs/lane) ----
    const int segbase = c0 + kb * 64 + wv * 16 + col;
    const int mseg0 = segids[segbase];
    const int mseg1 = segids[segbase + 256];

    // ---- prologue: tile 0 A loads (depth-1) ----
    const float* arow = videos + (size_t)(c0 + wv * 16 + col) * 2048 + h * DD + kb * 8;
    float4 av[8];
    #pragma unroll
    for (int q = 0; q < 4; ++q){
        av[2*q]   = *(const float4*)(arow + q * 32);
        av[2*q+1] = *(const float4*)(arow + q * 32 + 4);
    }

    u16*       parkp = sAh + (wv * 16 + col) * LDA + kb * 8;
    const u16* rdp   = sAh + (wv * 16) * LDA + lane * 2;

    __syncthreads();   // sBl visible

    int   cur = -1;
    float ax = 0.f, ay = 0.f, dn = 0.f;

    for (int t = 0; t < NTILE; ++t){
        // ---- cvt all K up-front (av dies here), park A-hi ----
        bf16x8 aHk[4], aLk[4];
        #pragma unroll
        for (int ks = 0; ks < 4; ++ks){
            cvt8(av[2*ks], av[2*ks+1], aHk[ks], aLk[ks]);
            *(bf16x8*)(parkp + ks * 32) = aHk[ks];
        }
        // ---- prefetch next tile's A (full-tile distance) ----
        if (t + 1 < NTILE){
            const float* nrow = arow + (size_t)(t + 1) * BT * 2048;
            #pragma unroll
            for (int q = 0; q < 4; ++q){
                av[2*q]   = *(const float4*)(nrow + q * 32);
                av[2*q+1] = *(const float4*)(nrow + q * 32 + 4);
            }
        }
        // ---- MFMA: pre-tanh alpha [16 x 64], bf16x3 compensated ----
        f32x4 acc[4] = {};
        #pragma unroll
        for (int ks = 0; ks < 4; ++ks){
            #pragma unroll
            for (int nt = 0; nt < 4; ++nt){
                bf16x8 bL = *(const bf16x8*)(sBl + (nt * 16 + col) * LDA + kb * 8 + ks * 32);
                acc[nt] = __builtin_amdgcn_mfma_f32_16x16x32_bf16(aHk[ks], bh[ks][nt], acc[nt], 0, 0, 0);
                acc[nt] = __builtin_amdgcn_mfma_f32_16x16x32_bf16(aLk[ks], bh[ks][nt], acc[nt], 0, 0, 0);
                acc[nt] = __builtin_amdgcn_mfma_f32_16x16x32_bf16(aHk[ks], bL,         acc[nt], 0, 0, 0);
            }
        }
        // ---- tanh -> *w -> 16-lane-group reduce over L -> e ----
        float e4[4];
        #pragma unroll
        for (int r = 0; r < 4; ++r){
            float s = 0.f;
            #pragma unroll
            for (int nt = 0; nt < 4; ++nt)
                s += fast_tanh(acc[nt][r]) * wl[nt];
            #pragma unroll
            for (int m = 1; m < 16; m <<= 1)
                s += __shfl_xor(s, m, 64);
            e4[r] = __builtin_amdgcn_exp2f(s * 1.4426950408889634f);
        }

        // ---- per-wave segment accumulation over this tile's 16 rows ----
        const int msel = (t < 4) ? mseg0 : mseg1;
        #pragma unroll
        for (int j = 0; j < 16; ++j){
            float ej = __shfl(e4[j & 3], (j >> 2) * 16);
            int   s  = __shfl(msel, (t & 3) * 16 + j);
            if (s != cur){                          // wave-uniform branch
                if (cur >= 0){
                    float* dst = hsum + ((size_t)cur * NH + h) * DD + lane * 2;
                    atomicAdd(dst, ax); atomicAdd(dst + 1, ay);
                    if (lane == 0) atomicAdd(&denom[cur * NH + h], dn);
                }
                ax = 0.f; ay = 0.f; dn = 0.f; cur = s;
            }
            u32 uh = *(const u32*)(rdp + j * LDA);
            ax += ej * __uint_as_float(uh << 16);
            ay += ej * __uint_as_float(uh & 0xffff0000u);
            dn += ej;
        }
    }
    // ---- final flush ----
    if (cur >= 0){
        float* dst = hsum + ((size_t)cur * NH + h) * DD + lane * 2;
        atomicAdd(dst, ax); atomicAdd(dst + 1, ay);
        if (lane == 0) atomicAdd(&denom[cur * NH + h], dn);
    }
}

// ---------------- finalize ----------------
__global__ void finalize(const float* __restrict__ hsum, const float* __restrict__ denom,
                         const float* __restrict__ W_out, const float* __restrict__ b_out,
                         float* __restrict__ out)
{
    const int s = blockIdx.x;
    const int tid = threadIdx.x;
    float part = 0.f;
    for (int f = tid; f < 2048; f += 256){
        int hh = f >> 7, d = f & 127;
        float den = denom[s * NH + hh];
        if (den > 0.f)
            part += hsum[((size_t)s * NH + hh) * DD + d] / (den * SCALE) * W_out[f];
    }
    #pragma unroll
    for (int m = 1; m < 64; m <<= 1) part += __shfl_xor(part, m, 64);
    __shared__ float red[4];
    if ((tid & 63) == 0) red[tid >> 6] = part;
    __syncthreads();
    if (tid == 0) out[s] = red[0] + red[1] + red[2] + red[3] + b_out[0];
}

extern "C" void kernel_launch(void* const* d_in, const int* in_sizes, int n_in,
                              void* d_out, int out_size, void* d_ws, size_t ws_size,
                              hipStream_t stream)
{
    const float* videos = (const float*)d_in[0];
    const int*   segids = (const int*)  d_in[1];
    const float* V      = (const float*)d_in[2];
    const float* w      = (const float*)d_in[3];
    const float* W_out  = (const float*)d_in[4];
    const float* b_out  = (const float*)d_in[5];
    float* out = (float*)d_out;

    // ws layout: hsum[S*H*D] f32 | denom[S*H] f32 | Vh[H*L*D] u16 | Vl[H*L*D] u16
    float* hsum  = (float*)d_ws;
    float* denom = hsum + (NSEG * NH * DD);
    u16*   Vh    = (u16*)(denom + NSEG * NH);
    u16*   Vl    = Vh + (NH * LL * DD);

    prep_split<<<dim3((NH * LL * DD) / 256), dim3(256), 0, stream>>>(V, Vh, Vl, hsum, denom);
    medvid_main<<<dim3(NCHUNK, NH), dim3(256), 0, stream>>>(videos, segids, Vh, Vl, w, hsum, denom);
    finalize<<<dim3(NSEG), dim3(256), 0, stream>>>(hsum, denom, W_out, b_out, out);
}

// Round 8
// 156.098 us; speedup vs baseline: 2.4949x; 1.6766x over previous
//
#include <hip/hip_runtime.h>

typedef unsigned short u16;
typedef unsigned int   u32;
typedef __bf16 bf16x8 __attribute__((ext_vector_type(8)));
typedef u16    u16x8  __attribute__((ext_vector_type(8)));
typedef float  f32x4  __attribute__((ext_vector_type(4)));

#define T_TOT  65536
#define NSEG   64
#define NH     16
#define DD     128
#define LL     64
#define BT     64
#define CHUNK  512           // frames per block
#define NTILE  8             // CHUNK / BT
#define NCHUNK 128           // T_TOT / CHUNK
#define LDA    136           // u16 row stride (272 B)
#define SCALE  11.313708498984761f   // sqrt(128)

__device__ __forceinline__ u16 f2bf_rne(float x){
    u32 u = __float_as_uint(x);
    u32 r = u + 0x7fffu + ((u >> 16) & 1u);
    return (u16)(r >> 16);
}
__device__ __forceinline__ float bf2f(u16 h){
    return __uint_as_float(((u32)h) << 16);
}
__device__ __forceinline__ float fast_tanh(float x){
    float e = __builtin_amdgcn_exp2f(x * 2.8853900817779268f);  // 2*log2(e)
    return 1.0f - 2.0f * __builtin_amdgcn_rcpf(1.0f + e);
}

// sum across the 16-lane group via DPP (VALU-only, no LDS-unit round-trips)
__device__ __forceinline__ float row16_sum(float x){
    int v;
    v = __builtin_amdgcn_update_dpp(0, __float_as_int(x), 0xB1, 0xf, 0xf, true);  // quad_perm(1,0,3,2)
    x += __int_as_float(v);
    v = __builtin_amdgcn_update_dpp(0, __float_as_int(x), 0x4E, 0xf, 0xf, true);  // quad_perm(2,3,0,1)
    x += __int_as_float(v);
    v = __builtin_amdgcn_update_dpp(0, __float_as_int(x), 0x124, 0xf, 0xf, true); // row_ror:4
    x += __int_as_float(v);
    v = __builtin_amdgcn_update_dpp(0, __float_as_int(x), 0x128, 0xf, 0xf, true); // row_ror:8
    x += __int_as_float(v);
    return x;
}

// split 8 fp32 -> bf16 hi + lo (error-compensated), in registers
__device__ __forceinline__ void cvt8(const float4 a, const float4 b,
                                     bf16x8& hi, bf16x8& lo){
    float xs[8] = {a.x, a.y, a.z, a.w, b.x, b.y, b.z, b.w};
    union { u16x8 u; bf16x8 b; } H, L;
    #pragma unroll
    for (int j = 0; j < 8; ++j){
        u32 u = __float_as_uint(xs[j]);
        u32 r = u + 0x7fffu + ((u >> 16) & 1u);
        H.u[j] = (u16)(r >> 16);
        float d = xs[j] - __uint_as_float(r & 0xffff0000u);
        u32 v = __float_as_uint(d);
        u32 s = v + 0x7fffu + ((v >> 16) & 1u);
        L.u[j] = (u16)(s >> 16);
    }
    hi = H.b; lo = L.b;
}

// ---------------- prep: split V into bf16 hi/lo + zero accumulators ----------------
__global__ void prep_split(const float* __restrict__ V,
                           u16* __restrict__ Vh, u16* __restrict__ Vl,
                           float* __restrict__ hsum, float* __restrict__ denom){
    int idx = blockIdx.x * 256 + threadIdx.x;   // 131072 threads
    float x = V[idx];
    u16 hi = f2bf_rne(x);
    Vh[idx] = hi;
    Vl[idx] = f2bf_rne(x - bf2f(hi));
    hsum[idx] = 0.0f;                            // hsum is exactly 131072 floats
    if (idx < NSEG * NH) denom[idx] = 0.0f;
}

// ---------------- main: R3 structure + DPP reduce + readlane broadcasts ----------------
__global__ __launch_bounds__(256, 2) void medvid_main(
    const float* __restrict__ videos, const int* __restrict__ segids,
    const u16* __restrict__ Vh, const u16* __restrict__ Vl,
    const float* __restrict__ w,
    float* __restrict__ hsum, float* __restrict__ denom)
{
    __shared__ u16 sAh[BT * LDA];   // A-hi park, per-wave 16-row regions (17.4 KB)

    const int tid  = threadIdx.x;
    const int h    = blockIdx.y;
    const int c0   = blockIdx.x * CHUNK;
    const int lane = tid & 63;
    const int wv   = tid >> 6;      // wave id = 16-frame strip within tile
    const int col  = lane & 15;
    const int kb   = lane >> 4;

    // ---- B fragments: tile-invariant, fully in registers (128 VGPR) ----
    bf16x8 bh[4][4], bl[4][4];
    #pragma unroll
    for (int ks = 0; ks < 4; ++ks){
        #pragma unroll
        for (int nt = 0; nt < 4; ++nt){
            const int off = (h * LL + nt * 16 + col) * DD + kb * 8 + ks * 32;
            bh[ks][nt] = *(const bf16x8*)(Vh + off);
            bl[ks][nt] = *(const bf16x8*)(Vl + off);
        }
    }
    float wl[4];
    #pragma unroll
    for (int nt = 0; nt < 4; ++nt) wl[nt] = w[h * LL + nt * 16 + col];

    // ---- this wave's 128 segment ids (2 regs/lane) ----
    const int segbase = c0 + kb * 64 + wv * 16 + col;
    const int mseg0 = segids[segbase];
    const int mseg1 = segids[segbase + 256];

    // ---- prologue: tile 0 A loads (depth-1) ----
    const float* arow = videos + (size_t)(c0 + wv * 16 + col) * 2048 + h * DD + kb * 8;
    float4 av[8];
    #pragma unroll
    for (int q = 0; q < 4; ++q){
        av[2*q]   = *(const float4*)(arow + q * 32);
        av[2*q+1] = *(const float4*)(arow + q * 32 + 4);
    }

    u16*       parkp = sAh + (wv * 16 + col) * LDA + kb * 8;
    const u16* rdp   = sAh + (wv * 16) * LDA + lane * 2;

    int   cur = -1;
    float ax = 0.f, ay = 0.f, dn = 0.f;

    for (int t = 0; t < NTILE; ++t){
        // ---- MFMA: pre-tanh alpha [16 x 64], bf16x3 compensated ----
        f32x4 acc[4] = {};
        #pragma unroll
        for (int ks = 0; ks < 4; ++ks){
            bf16x8 aH, aL;
            cvt8(av[2*ks], av[2*ks+1], aH, aL);
            *(bf16x8*)(parkp + ks * 32) = aH;        // park hi for phase-4
            #pragma unroll
            for (int nt = 0; nt < 4; ++nt){
                acc[nt] = __builtin_amdgcn_mfma_f32_16x16x32_bf16(aH, bh[ks][nt], acc[nt], 0, 0, 0);
                acc[nt] = __builtin_amdgcn_mfma_f32_16x16x32_bf16(aL, bh[ks][nt], acc[nt], 0, 0, 0);
                acc[nt] = __builtin_amdgcn_mfma_f32_16x16x32_bf16(aH, bl[ks][nt], acc[nt], 0, 0, 0);
            }
        }
        // ---- prefetch next tile's A ----
        if (t + 1 < NTILE){
            const float* nrow = arow + (size_t)(t + 1) * BT * 2048;
            #pragma unroll
            for (int q = 0; q < 4; ++q){
                av[2*q]   = *(const float4*)(nrow + q * 32);
                av[2*q+1] = *(const float4*)(nrow + q * 32 + 4);
            }
        }
        // ---- tanh -> *w -> DPP reduce over L -> e ----
        float e4[4];
        #pragma unroll
        for (int r = 0; r < 4; ++r){
            float s = 0.f;
            #pragma unroll
            for (int nt = 0; nt < 4; ++nt)
                s += fast_tanh(acc[nt][r]) * wl[nt];
            s = row16_sum(s);
            e4[r] = __builtin_amdgcn_exp2f(s * 1.4426950408889634f);
        }

        // ---- per-wave segment accumulation; e and seg broadcast via readlane (SGPR) ----
        const int msel = (t < 4) ? mseg0 : mseg1;
        const int tb   = (t & 3) * 16;
        #pragma unroll
        for (int j = 0; j < 16; ++j){
            float ej = __int_as_float(__builtin_amdgcn_readlane(__float_as_int(e4[j & 3]), (j >> 2) * 16));
            int   s  = __builtin_amdgcn_readlane(msel, tb + j);   // SGPR, wave-uniform
            if (s != cur){                          // scalar branch
                if (cur >= 0){
                    float* dst = hsum + ((size_t)cur * NH + h) * DD + lane * 2;
                    atomicAdd(dst, ax); atomicAdd(dst + 1, ay);
                    if (lane == 0) atomicAdd(&denom[cur * NH + h], dn);
                }
                ax = 0.f; ay = 0.f; dn = 0.f; cur = s;
            }
            u32 uh = *(const u32*)(rdp + j * LDA);
            ax += ej * __uint_as_float(uh << 16);
            ay += ej * __uint_as_float(uh & 0xffff0000u);
            dn += ej;
        }
    }
    // ---- final flush ----
    if (cur >= 0){
        float* dst = hsum + ((size_t)cur * NH + h) * DD + lane * 2;
        atomicAdd(dst, ax); atomicAdd(dst + 1, ay);
        if (lane == 0) atomicAdd(&denom[cur * NH + h], dn);
    }
}

// ---------------- finalize ----------------
__global__ void finalize(const float* __restrict__ hsum, const float* __restrict__ denom,
                         const float* __restrict__ W_out, const float* __restrict__ b_out,
                         float* __restrict__ out)
{
    const int s = blockIdx.x;
    const int tid = threadIdx.x;
    float part = 0.f;
    for (int f = tid; f < 2048; f += 256){
        int hh = f >> 7, d = f & 127;
        float den = denom[s * NH + hh];
        if (den > 0.f)
            part += hsum[((size_t)s * NH + hh) * DD + d] / (den * SCALE) * W_out[f];
    }
    #pragma unroll
    for (int m = 1; m < 64; m <<= 1) part += __shfl_xor(part, m, 64);
    __shared__ float red[4];
    if ((tid & 63) == 0) red[tid >> 6] = part;
    __syncthreads();
    if (tid == 0) out[s] = red[0] + red[1] + red[2] + red[3] + b_out[0];
}

extern "C" void kernel_launch(void* const* d_in, const int* in_sizes, int n_in,
                              void* d_out, int out_size, void* d_ws, size_t ws_size,
                              hipStream_t stream)
{
    const float* videos = (const float*)d_in[0];
    const int*   segids = (const int*)  d_in[1];
    const float* V      = (const float*)d_in[2];
    const float* w      = (const float*)d_in[3];
    const float* W_out  = (const float*)d_in[4];
    const float* b_out  = (const float*)d_in[5];
    float* out = (float*)d_out;

    // ws layout: hsum[S*H*D] f32 | denom[S*H] f32 | Vh[H*L*D] u16 | Vl[H*L*D] u16
    float* hsum  = (float*)d_ws;
    float* denom = hsum + (NSEG * NH * DD);
    u16*   Vh    = (u16*)(denom + NSEG * NH);
    u16*   Vl    = Vh + (NH * LL * DD);

    prep_split<<<dim3((NH * LL * DD) / 256), dim3(256), 0, stream>>>(V, Vh, Vl, hsum, denom);
    medvid_main<<<dim3(NCHUNK, NH), dim3(256), 0, stream>>>(videos, segids, Vh, Vl, w, hsum, denom);
    finalize<<<dim3(NSEG), dim3(256), 0, stream>>>(hsum, denom, W_out, b_out, out);
}